// Round 1
// baseline (234.515 us; speedup 1.0000x reference)
//
#include <hip/hip_runtime.h>
#include <hip/hip_bf16.h>

typedef __attribute__((ext_vector_type(8))) short bf16x8;
typedef __attribute__((ext_vector_type(4))) short short4v;
typedef __attribute__((ext_vector_type(4))) float f32x4;
typedef unsigned int u32;

// ---------- helpers ----------
__device__ __forceinline__ short f2bf(float f) {
    union { float f; u32 i; } c; c.f = f;
    u32 r = c.i + 0x7FFFu + ((c.i >> 16) & 1u);   // RNE
    return (short)(r >> 16);
}
__device__ __forceinline__ u32 pack2bf(float lo, float hi) {
    return ((u32)(unsigned short)f2bf(hi) << 16) | (u32)(unsigned short)f2bf(lo);
}
__device__ __forceinline__ f32x4 mfma16(bf16x8 a, bf16x8 b, f32x4 c) {
    return __builtin_amdgcn_mfma_f32_16x16x32_bf16(a, b, c, 0, 0, 0);
}
__device__ __forceinline__ void load_lds16(const void* g, void* l) {
    __builtin_amdgcn_global_load_lds(
        (const __attribute__((address_space(1))) u32*)g,
        (__attribute__((address_space(3))) u32*)l, 16, 0, 0);
}

// ---------- fp32 -> bf16 convert (x + 4 weights fused) ----------
__global__ __launch_bounds__(256) void cvt_all_kernel(
    const float* __restrict__ x, const float* __restrict__ wq,
    const float* __restrict__ wk, const float* __restrict__ wv,
    const float* __restrict__ wo, short* __restrict__ ws) {
    const int XV = (4096 * 1024) / 4;   // float4 count for x
    const int WV = (1024 * 1024) / 4;   // float4 count per weight
    int i = blockIdx.x * 256 + threadIdx.x;
    const float4* src; short4v* dst; int off;
    if (i < XV)            { src = (const float4*)x;  dst = (short4v*)(ws);           off = i; }
    else if (i < XV + WV)  { src = (const float4*)wq; dst = (short4v*)(ws + 4194304); off = i - XV; }
    else if (i < XV + 2*WV){ src = (const float4*)wk; dst = (short4v*)(ws + 5242880); off = i - XV - WV; }
    else if (i < XV + 3*WV){ src = (const float4*)wv; dst = (short4v*)(ws + 6291456); off = i - XV - 2*WV; }
    else                   { src = (const float4*)wo; dst = (short4v*)(ws + 7340032); off = i - XV - 3*WV; }
    float4 v = src[off];
    short4v o;
    o.x = f2bf(v.x); o.y = f2bf(v.y); o.z = f2bf(v.z); o.w = f2bf(v.w);
    dst[off] = o;
}

// ---------- shared GEMM mainloop: C[128x128] += A[128xK] * B[128xK]^T ----------
// LDS is fragment-ordered: frag f (= mtile*2 + kchunk) occupies 1KB, lane piece at
// f*512 + lane*8 shorts -> ds_read_b128 is conflict-free (16B stride across lanes).
__device__ __forceinline__ void gemm_mainloop(
    const short* __restrict__ A, const short* __restrict__ Bm,
    short* lds, int mbase, int nbase, int wave, int lane, f32x4 acc[4][4]) {
    const int K = 1024;
    const int lr = lane & 15, lg = lane >> 4;
    const int wm = wave >> 1, wn = wave & 1;
    for (int k0 = 0; k0 < K; k0 += 64) {
        __syncthreads();
        #pragma unroll
        for (int issue = 0; issue < 4; ++issue) {
            int f = issue * 4 + wave;
            int mt = f >> 1, kc = f & 1;
            load_lds16(A  + (size_t)(mbase + mt*16 + lr)*K + (k0 + kc*32 + lg*8), lds + f*512);
            load_lds16(Bm + (size_t)(nbase + mt*16 + lr)*K + (k0 + kc*32 + lg*8), lds + 8192 + f*512);
        }
        __syncthreads();
        #pragma unroll
        for (int kc = 0; kc < 2; ++kc) {
            bf16x8 af[4], bfv[4];
            #pragma unroll
            for (int mi = 0; mi < 4; ++mi)
                af[mi] = *(const bf16x8*)(lds + ((wm*4 + mi)*2 + kc)*512 + lane*8);
            #pragma unroll
            for (int ni = 0; ni < 4; ++ni)
                bfv[ni] = *(const bf16x8*)(lds + 8192 + ((wn*4 + ni)*2 + kc)*512 + lane*8);
            #pragma unroll
            for (int mi = 0; mi < 4; ++mi)
                #pragma unroll
                for (int ni = 0; ni < 4; ++ni)
                    acc[mi][ni] = mfma16(af[mi], bfv[ni], acc[mi][ni]);
        }
    }
}

// ---------- fused QKV projection ----------
// grid.x: 0..23 -> (sel = x>>3) in {Q,K,V}, ncol tile = (x&7)*128 ; grid.y: m tile
__global__ __launch_bounds__(256) void gemm_qkv_kernel(
    const short* __restrict__ xb, const short* __restrict__ wqb,
    const short* __restrict__ wkb, const short* __restrict__ wvb,
    short* __restrict__ Qh, short* __restrict__ Kh, short* __restrict__ Vt) {
    __shared__ short lds[16384];
    const int wave = threadIdx.x >> 6, lane = threadIdx.x & 63;
    const int lr = lane & 15, lg = lane >> 4;
    const int sel = blockIdx.x >> 3;
    const int nbase = (blockIdx.x & 7) * 128;
    const int mbase = blockIdx.y * 128;
    const short* Bm = (sel == 0) ? wqb : (sel == 1) ? wkb : wvb;

    f32x4 acc[4][4];
    #pragma unroll
    for (int i = 0; i < 4; ++i)
        #pragma unroll
        for (int j = 0; j < 4; ++j) acc[i][j] = f32x4{0.f, 0.f, 0.f, 0.f};

    gemm_mainloop(xb, Bm, lds, mbase, nbase, wave, lane, acc);

    const int wm = wave >> 1, wn = wave & 1;
    #pragma unroll
    for (int mi = 0; mi < 4; ++mi) {
        int m0 = mbase + wm*64 + mi*16 + lg*4;
        #pragma unroll
        for (int ni = 0; ni < 4; ++ni) {
            int nc = nbase + wn*64 + ni*16 + lr;
            int h = nc >> 6, d = nc & 63;
            f32x4 v = acc[mi][ni];
            if (sel == 2) {
                // V transposed per head: Vt[b][h][d][npos], 4 consecutive npos -> 8B store
                int bi = m0 >> 11, np = m0 & 2047;
                short4v o;
                o.x = f2bf(v.x); o.y = f2bf(v.y); o.z = f2bf(v.z); o.w = f2bf(v.w);
                *(short4v*)&Vt[((size_t)(bi*16 + h)*64 + d)*2048 + np] = o;
            } else {
                short* dstb = (sel == 0) ? Qh : Kh;
                float sc = (sel == 0) ? 0.125f : 1.0f;   // fold 1/sqrt(64) into Q
                #pragma unroll
                for (int r = 0; r < 4; ++r) {
                    int m = m0 + r; int bi = m >> 11, np = m & 2047;
                    dstb[((size_t)(bi*16 + h)*2048 + np)*64 + d] = f2bf(v[r] * sc);
                }
            }
        }
    }
}

// ---------- output projection: out = AO @ Wo^T + bo (fp32 out) ----------
__global__ __launch_bounds__(256) void gemm_out_kernel(
    const short* __restrict__ AO, const short* __restrict__ wob,
    const float* __restrict__ bias, float* __restrict__ out) {
    __shared__ short lds[16384];
    const int wave = threadIdx.x >> 6, lane = threadIdx.x & 63;
    const int lr = lane & 15, lg = lane >> 4;
    const int nbase = blockIdx.x * 128;
    const int mbase = blockIdx.y * 128;

    f32x4 acc[4][4];
    #pragma unroll
    for (int i = 0; i < 4; ++i)
        #pragma unroll
        for (int j = 0; j < 4; ++j) acc[i][j] = f32x4{0.f, 0.f, 0.f, 0.f};

    gemm_mainloop(AO, wob, lds, mbase, nbase, wave, lane, acc);

    const int wm = wave >> 1, wn = wave & 1;
    #pragma unroll
    for (int mi = 0; mi < 4; ++mi) {
        int m0 = mbase + wm*64 + mi*16 + lg*4;
        #pragma unroll
        for (int ni = 0; ni < 4; ++ni) {
            int nc = nbase + wn*64 + ni*16 + lr;
            float bj = bias[nc];
            f32x4 v = acc[mi][ni];
            #pragma unroll
            for (int r = 0; r < 4; ++r)
                out[(size_t)(m0 + r)*1024 + nc] = v[r] + bj;
        }
    }
}

// ---------- flash-style 2-pass adaptive-temperature attention ----------
// One wave owns 32 query rows (two 16-col groups A,B). Swapped QK^T: mfma(K,Q)
// -> S^T frag: col(lane&15)=q, row(lg*4+r)=k. Per-q stats reduce over lanes
// xor 16/32. Pass2 recomputes S^T, P=exp(beta*l), repack to PV B-operand via
// shfl, O^T += V^T P^T with contiguous Vt loads.
__global__ __launch_bounds__(256) void attn_kernel(
    const short* __restrict__ Qh, const short* __restrict__ Kh,
    const short* __restrict__ Vt, short* __restrict__ AO) {
    const int bh   = blockIdx.x;                    // b*16+h
    const int lane = threadIdx.x & 63;
    const int wave = threadIdx.x >> 6;
    const int q0   = blockIdx.y * 128 + wave * 32;
    const int lr = lane & 15, lg = lane >> 4;
    const short* Q = Qh + (size_t)bh * (2048 * 64);
    const short* K = Kh + (size_t)bh * (2048 * 64);
    const short* V = Vt + (size_t)bh * (64 * 2048);
    const int qa = q0 + lr, qb = q0 + 16 + lr;

    bf16x8 qfA[2], qfB[2];
    #pragma unroll
    for (int c = 0; c < 2; ++c) {
        qfA[c] = *(const bf16x8*)&Q[(size_t)qa*64 + c*32 + lg*8];
        qfB[c] = *(const bf16x8*)&Q[(size_t)qb*64 + c*32 + lg*8];
    }

    // ---- pass 1: entropy stats (ref-max 0; logits are O(1) by construction) ----
    float sA = 0.f, tA = 0.f, sB = 0.f, tB = 0.f;
    const int ktmax = (q0 + 31) >> 4;
    for (int kt = 0; kt <= ktmax; ++kt) {
        const short* Kr = &K[(size_t)(kt*16 + lr)*64 + lg*8];
        bf16x8 kf0 = *(const bf16x8*)Kr;
        bf16x8 kf1 = *(const bf16x8*)(Kr + 32);
        f32x4 dA = {0.f,0.f,0.f,0.f}, dB = {0.f,0.f,0.f,0.f};
        dA = mfma16(kf0, qfA[0], dA); dA = mfma16(kf1, qfA[1], dA);
        dB = mfma16(kf0, qfB[0], dB); dB = mfma16(kf1, qfB[1], dB);
        int kb = kt*16 + lg*4;
        #pragma unroll
        for (int r = 0; r < 4; ++r) {
            float lA = (kb + r <= qa) ? dA[r] : -1e30f;
            float eA = __expf(lA); sA += eA; tA += eA * lA;
            float lB = (kb + r <= qb) ? dB[r] : -1e30f;
            float eB = __expf(lB); sB += eB; tB += eB * lB;
        }
    }
    sA += __shfl_xor(sA, 16); tA += __shfl_xor(tA, 16);
    sA += __shfl_xor(sA, 32); tA += __shfl_xor(tA, 32);
    sB += __shfl_xor(sB, 16); tB += __shfl_xor(tB, 16);
    sB += __shfl_xor(sB, 32); tB += __shfl_xor(tB, 32);
    float HA = __logf(sA) - tA / sA;
    float HB = __logf(sB) - tB / sB;
    float betaA = 1.f, betaB = 1.f;
    if (HA > 0.5f)
        betaA = fmaxf((((-0.037f*HA + 0.481f)*HA - 2.3f)*HA + 4.917f)*HA - 1.791f, 1.f);
    if (HB > 0.5f)
        betaB = fmaxf((((-0.037f*HB + 0.481f)*HB - 2.3f)*HB + 4.917f)*HB - 1.791f, 1.f);

    // ---- pass 2: softmax(beta*l) and PV ----
    f32x4 oA[4], oB[4];
    #pragma unroll
    for (int dc = 0; dc < 4; ++dc) { oA[dc] = f32x4{0.f,0.f,0.f,0.f}; oB[dc] = f32x4{0.f,0.f,0.f,0.f}; }
    float s2A = 0.f, s2B = 0.f;
    const int nch = (q0 >> 5) + 1;              // k in [0, q0+32), chunks of 32
    for (int ch = 0; ch < nch; ++ch) {
        u32 pkA[2][2], pkB[2][2];
        #pragma unroll
        for (int t = 0; t < 2; ++t) {
            int kt = ch*2 + t;
            const short* Kr = &K[(size_t)(kt*16 + lr)*64 + lg*8];
            bf16x8 kf0 = *(const bf16x8*)Kr;
            bf16x8 kf1 = *(const bf16x8*)(Kr + 32);
            f32x4 dA = {0.f,0.f,0.f,0.f}, dB = {0.f,0.f,0.f,0.f};
            dA = mfma16(kf0, qfA[0], dA); dA = mfma16(kf1, qfA[1], dA);
            dB = mfma16(kf0, qfB[0], dB); dB = mfma16(kf1, qfB[1], dB);
            int kb = kt*16 + lg*4;
            float pA[4], pB[4];
            #pragma unroll
            for (int r = 0; r < 4; ++r) {
                pA[r] = (kb + r <= qa) ? __expf(betaA * dA[r]) : 0.f; s2A += pA[r];
                pB[r] = (kb + r <= qb) ? __expf(betaB * dB[r]) : 0.f; s2B += pB[r];
            }
            pkA[t][0] = pack2bf(pA[0], pA[1]); pkA[t][1] = pack2bf(pA[2], pA[3]);
            pkB[t][0] = pack2bf(pB[0], pB[1]); pkB[t][1] = pack2bf(pB[2], pB[3]);
        }
        // redistribute P^T into PV B-fragment: lane needs k = ch*32 + lg*8 + j
        union { bf16x8 v; u32 u[4]; } pfA, pfB;
        #pragma unroll
        for (int w = 0; w < 4; ++w) {
            int srcl = lr + ((((lg << 1) + (w >> 1)) & 3) << 4);
            u32 a0 = (u32)__shfl((int)pkA[0][w & 1], srcl);
            u32 a1 = (u32)__shfl((int)pkA[1][w & 1], srcl);
            pfA.u[w] = (lg >= 2) ? a1 : a0;
            u32 b0 = (u32)__shfl((int)pkB[0][w & 1], srcl);
            u32 b1 = (u32)__shfl((int)pkB[1][w & 1], srcl);
            pfB.u[w] = (lg >= 2) ? b1 : b0;
        }
        #pragma unroll
        for (int dc = 0; dc < 4; ++dc) {
            bf16x8 vf = *(const bf16x8*)&V[(size_t)(dc*16 + lr)*2048 + ch*32 + lg*8];
            oA[dc] = mfma16(vf, pfA.v, oA[dc]);
            oB[dc] = mfma16(vf, pfB.v, oB[dc]);
        }
    }
    s2A += __shfl_xor(s2A, 16); s2A += __shfl_xor(s2A, 32);
    s2B += __shfl_xor(s2B, 16); s2B += __shfl_xor(s2B, 32);
    float invA = 1.f / s2A, invB = 1.f / s2B;

    int b = bh >> 4, h = bh & 15;
    size_t rowA = ((size_t)(b*2048 + qa))*1024 + h*64;
    size_t rowB = ((size_t)(b*2048 + qb))*1024 + h*64;
    #pragma unroll
    for (int dc = 0; dc < 4; ++dc) {
        short4v wa, wb;
        #pragma unroll
        for (int r = 0; r < 4; ++r) {
            wa[r] = f2bf(oA[dc][r] * invA);
            wb[r] = f2bf(oB[dc][r] * invB);
        }
        *(short4v*)&AO[rowA + dc*16 + lg*4] = wa;
        *(short4v*)&AO[rowB + dc*16 + lg*4] = wb;
    }
}

// ---------- launch ----------
extern "C" void kernel_launch(void* const* d_in, const int* in_sizes, int n_in,
                              void* d_out, int out_size, void* d_ws, size_t ws_size,
                              hipStream_t stream) {
    const float* x  = (const float*)d_in[0];
    const float* Wq = (const float*)d_in[1];
    const float* Wk = (const float*)d_in[2];
    const float* Wv = (const float*)d_in[3];
    const float* Wo = (const float*)d_in[4];
    const float* bo = (const float*)d_in[5];
    float* out = (float*)d_out;
    short* ws = (short*)d_ws;

    // workspace layout (shorts): 48 MB total
    short* xb  = ws;              // [4096][1024] bf16 x
    short* wqb = ws + 4194304;
    short* wkb = ws + 5242880;
    short* wvb = ws + 6291456;
    short* wob = ws + 7340032;
    short* Qh  = ws + 8388608;    // [2][16][2048][64], scaled by 0.125
    short* Kh  = ws + 12582912;   // [2][16][2048][64]
    short* Vt  = ws + 16777216;   // [2][16][64][2048]
    short* AO  = ws + 20971520;   // [4096][1024] attention output

    cvt_all_kernel<<<8192, 256, 0, stream>>>(x, Wq, Wk, Wv, Wo, ws);
    gemm_qkv_kernel<<<dim3(24, 32), 256, 0, stream>>>(xb, wqb, wkb, wvb, Qh, Kh, Vt);
    attn_kernel<<<dim3(32, 16), 256, 0, stream>>>(Qh, Kh, Vt, AO);
    gemm_out_kernel<<<dim3(8, 32), 256, 0, stream>>>(AO, wob, bo, out);
}